// Round 2
// baseline (260.762 us; speedup 1.0000x reference)
//
#include <hip/hip_runtime.h>

typedef unsigned short u16;
typedef __attribute__((ext_vector_type(8))) short bf16x8;
typedef __attribute__((ext_vector_type(4))) float f32x4;

__device__ __forceinline__ u16 f2bf(float f) {
    unsigned u = __float_as_uint(f);
    unsigned r = (u + 0x7fffu + ((u >> 16) & 1u)) >> 16;
    return (u16)r;
}

#define NB 8
#define NC 256
#define NK 9
#define NH 64
#define NW 64
#define NP 4096

// ---------------- pass 1: key_feature = w_refer @ key + b_refer (bf16 MFMA, LDS-free) ----
// Fragments loaded straight from global (w/key are L2-resident at this size).
__global__ __launch_bounds__(256) void kf_gemm(const float* __restrict__ key,
                                               const float* __restrict__ w_refer,
                                               const float* __restrict__ b_refer,
                                               float* __restrict__ kf)
{
    const int pt  = blockIdx.x;            // 256 pixel tiles (32 per batch)
    const int b   = pt >> 5;
    const int p0  = (pt & 31) << 7;
    const int co0 = blockIdx.y << 7;
    const int lane = threadIdx.x & 63, wid = threadIdx.x >> 6;
    const int wm = wid & 1, wn = wid >> 1;          // wave quadrant: 64co x 64px
    const int fr = lane & 15, kq = (lane >> 4) << 3;

    f32x4 acc[4][4];
    #pragma unroll
    for (int i = 0; i < 4; ++i)
        #pragma unroll
        for (int j = 0; j < 4; ++j) acc[i][j] = (f32x4){0.f, 0.f, 0.f, 0.f};

    for (int ks = 0; ks < 8; ++ks) {
        const int k0 = (ks << 5) + kq;              // this lane's k-octet base
        bf16x8 af[4], bfv[4];
        // A fragment: w_refer[co0 + wm*64 + mi*16 + fr][k0 .. k0+7]  (k-contiguous)
        #pragma unroll
        for (int mi = 0; mi < 4; ++mi) {
            const float* src = &w_refer[(size_t)(co0 + (wm << 6) + (mi << 4) + fr) * NC + k0];
            float4 v0 = *(const float4*)src;
            float4 v1 = *(const float4*)(src + 4);
            bf16x8 a;
            a[0] = (short)f2bf(v0.x); a[1] = (short)f2bf(v0.y);
            a[2] = (short)f2bf(v0.z); a[3] = (short)f2bf(v0.w);
            a[4] = (short)f2bf(v1.x); a[5] = (short)f2bf(v1.y);
            a[6] = (short)f2bf(v1.z); a[7] = (short)f2bf(v1.w);
            af[mi] = a;
        }
        // B fragment: key[k0+j][px = p0 + wn*64 + ni*16 + fr]  (k strided by 4096)
        #pragma unroll
        for (int ni = 0; ni < 4; ++ni) {
            const float* src = &key[((size_t)b * NC + k0) * NP + p0 + (wn << 6) + (ni << 4) + fr];
            bf16x8 bv;
            #pragma unroll
            for (int j = 0; j < 8; ++j) bv[j] = (short)f2bf(src[(size_t)j * NP]);
            bfv[ni] = bv;
        }
        #pragma unroll
        for (int mi = 0; mi < 4; ++mi)
            #pragma unroll
            for (int ni = 0; ni < 4; ++ni)
                acc[mi][ni] = __builtin_amdgcn_mfma_f32_16x16x32_bf16(af[mi], bfv[ni], acc[mi][ni], 0, 0, 0);
    }
    // D mapping (m89-verified): col = lane&15 (px), row = (lane>>4)*4 + reg (c_out)
    const int col = lane & 15, rbase = (lane >> 4) << 2;
    #pragma unroll
    for (int mi = 0; mi < 4; ++mi) {
        #pragma unroll
        for (int rr = 0; rr < 4; ++rr) {
            int co = co0 + (wm << 6) + (mi << 4) + rbase + rr;
            float bias = b_refer[co];
            float* dst = &kf[((size_t)b * NC + co) * NP + p0 + (wn << 6) + col];
            #pragma unroll
            for (int ni = 0; ni < 4; ++ni)
                dst[ni << 4] = acc[mi][ni][rr] + bias;
        }
    }
}

// --------- pass 2: attn/mask/offset heads + softmaxes + sample coords --------------
__global__ __launch_bounds__(256) void head_pass(const float* __restrict__ query,
                                                 const float* __restrict__ gumbel,
                                                 const float* __restrict__ w_attn, const float* __restrict__ b_attn,
                                                 const float* __restrict__ w_mask, const float* __restrict__ b_mask,
                                                 const float* __restrict__ w_off,  const float* __restrict__ b_off,
                                                 const int* __restrict__ temp_p,
                                                 float* __restrict__ aw, float* __restrict__ pyo,
                                                 float* __restrict__ pxo)
{
    __shared__ float Wf[36][256];
    __shared__ float partial[4][36][64];
    const int blk = blockIdx.x;
    const int b = blk >> 6, row = blk & 63;
    const int p0 = row << 6;
    const int t = threadIdx.x;
    const int tx = t & 63, ty = t >> 6;

    // stage all head weights (rows: 0..8 attn, 9..17 mask, 18..35 off)
    for (int ch = t; ch < 2304; ch += 256) {          // 36 rows x 64 float4
        int o = ch >> 6, c4 = (ch & 63) << 2;
        const float* src = (o < 9) ? &w_attn[o * NC + c4]
                       : (o < 18 ? &w_mask[(o - 9) * NC + c4]
                                 : &w_off[(o - 18) * NC + c4]);
        *(float4*)&Wf[o][c4] = *(const float4*)src;
    }
    // query slice in registers: c = ty*64 + i, pixel p0+tx
    float q[64];
    {
        const float* qb = &query[((size_t)b * NC + (ty << 6)) * NP + p0 + tx];
        #pragma unroll
        for (int i = 0; i < 64; ++i) q[i] = qb[(size_t)i * NP];
    }
    __syncthreads();
    #pragma unroll 1
    for (int o = 0; o < 36; ++o) {
        const float4* wrow = (const float4*)&Wf[o][ty << 6];
        float s = 0.f;
        #pragma unroll
        for (int c4 = 0; c4 < 16; ++c4) {
            float4 wv = wrow[c4];
            s += wv.x * q[c4 * 4] + wv.y * q[c4 * 4 + 1] + wv.z * q[c4 * 4 + 2] + wv.w * q[c4 * 4 + 3];
        }
        partial[ty][o][tx] = s;
    }
    __syncthreads();
    if (t < 64) {
        const int px = t;
        float v[36];
        #pragma unroll
        for (int o = 0; o < 36; ++o)
            v[o] = partial[0][o][px] + partial[1][o][px] + partial[2][o][px] + partial[3][o][px];
        // temp is a Python scalar 1 -> int32; defend against a float-bit-pattern ship
        int ti = temp_p[0];
        float tempf = (ti >= 1 && ti < (1 << 23)) ? (float)ti : __int_as_float(ti);
        float am[9], hs[9];
        float mx = -1e30f;
        #pragma unroll
        for (int k = 0; k < 9; ++k) {
            am[k] = v[k] + b_attn[k];
            float g = gumbel[((size_t)b * NK + k) * NP + p0 + px];
            hs[k] = (v[9 + k] + b_mask[k] + g) / tempf;
            mx = fmaxf(mx, hs[k]);
        }
        float ssum = 0.f;
        #pragma unroll
        for (int k = 0; k < 9; ++k) { hs[k] = __expf(hs[k] - mx); ssum += hs[k]; }
        float inv = 1.f / ssum;
        float lg[9]; float mx2 = -1e30f;
        #pragma unroll
        for (int k = 0; k < 9; ++k) { lg[k] = am[k] * (hs[k] * inv); mx2 = fmaxf(mx2, lg[k]); }
        float s2 = 0.f;
        #pragma unroll
        for (int k = 0; k < 9; ++k) { lg[k] = __expf(lg[k] - mx2); s2 += lg[k]; }
        float inv2 = 1.f / s2;
        #pragma unroll
        for (int k = 0; k < 9; ++k) {
            size_t idx = ((size_t)b * NK + k) * NP + p0 + px;
            aw[idx]  = lg[k] * inv2;
            pyo[idx] = (float)row + (v[18 + k] + b_off[k]);        // dy = off chan k
            pxo[idx] = (float)px  + (v[19 + k] + b_off[k + 1]);    // dx = off chan k+1 (!)
        }
    }
}

// --------------- pass 3: bilinear sample + weighted sum over K --------------------
__global__ __launch_bounds__(256) void sample_pass(const float* __restrict__ kf,
                                                   const float* __restrict__ aw,
                                                   const float* __restrict__ pyo,
                                                   const float* __restrict__ pxo,
                                                   float* __restrict__ out)
{
    const int blk = blockIdx.x;
    const int b = blk >> 6, row = blk & 63;
    const int t = threadIdx.x;
    const int tx = t & 63, ty = t >> 6;
    const float* kfb = kf + (size_t)b * NC * NP + (size_t)(ty << 6) * NP;
    float acc[64];
    #pragma unroll
    for (int j = 0; j < 64; ++j) acc[j] = 0.f;
    #pragma unroll 1
    for (int k = 0; k < NK; ++k) {
        size_t idx = ((size_t)b * NK + k) * NP + (row << 6) + tx;
        float a = aw[idx], pyv = pyo[idx], pxv = pxo[idx];
        float y0f = floorf(pyv), x0f = floorf(pxv);
        float wy = pyv - y0f, wx = pxv - x0f;
        int y0 = (int)y0f, x0 = (int)x0f;
        int y1 = y0 + 1, x1 = x0 + 1;
        float vy0 = (y0 >= 0 && y0 < NH) ? 1.f : 0.f;
        float vy1 = (y1 >= 0 && y1 < NH) ? 1.f : 0.f;
        float vx0 = (x0 >= 0 && x0 < NW) ? 1.f : 0.f;
        float vx1 = (x1 >= 0 && x1 < NW) ? 1.f : 0.f;
        int y0c = min(max(y0, 0), NH - 1), y1c = min(max(y1, 0), NH - 1);
        int x0c = min(max(x0, 0), NW - 1), x1c = min(max(x1, 0), NW - 1);
        float w00 = a * (1.f - wy) * (1.f - wx) * vy0 * vx0;
        float w01 = a * (1.f - wy) * wx * vy0 * vx1;
        float w10 = a * wy * (1.f - wx) * vy1 * vx0;
        float w11 = a * wy * wx * vy1 * vx1;
        int o00 = y0c * NW + x0c, o01 = y0c * NW + x1c;
        int o10 = y1c * NW + x0c, o11 = y1c * NW + x1c;
        #pragma unroll
        for (int j = 0; j < 64; ++j) {
            const float* pc = kfb + (size_t)j * NP;
            acc[j] += w00 * pc[o00] + w01 * pc[o01] + w10 * pc[o10] + w11 * pc[o11];
        }
    }
    float* ob = out + ((size_t)b * NC + (ty << 6)) * NP + (row << 6) + tx;
    #pragma unroll
    for (int j = 0; j < 64; ++j) ob[(size_t)j * NP] = acc[j];
}

extern "C" void kernel_launch(void* const* d_in, const int* in_sizes, int n_in,
                              void* d_out, int out_size, void* d_ws, size_t ws_size,
                              hipStream_t stream)
{
    const float* query   = (const float*)d_in[0];
    const float* key     = (const float*)d_in[1];
    const float* gumbel  = (const float*)d_in[2];
    const float* w_refer = (const float*)d_in[3];
    const float* b_refer = (const float*)d_in[4];
    const float* w_attn  = (const float*)d_in[5];
    const float* b_attn  = (const float*)d_in[6];
    const float* w_mask  = (const float*)d_in[7];
    const float* b_mask  = (const float*)d_in[8];
    const float* w_off   = (const float*)d_in[9];
    const float* b_off   = (const float*)d_in[10];
    const int*   temp    = (const int*)d_in[11];
    float* out = (float*)d_out;

    float* kf  = (float*)d_ws;                       // 8*256*4096 f32 = 33.5 MB
    float* awp = kf  + (size_t)NB * NC * NP;
    float* pyp = awp + (size_t)NB * NK * NP;
    float* pxp = pyp + (size_t)NB * NK * NP;

    kf_gemm<<<dim3(256, 2), 256, 0, stream>>>(key, w_refer, b_refer, kf);
    head_pass<<<dim3(NB * NH), 256, 0, stream>>>(query, gumbel, w_attn, b_attn,
                                                 w_mask, b_mask, w_off, b_off, temp,
                                                 awp, pyp, pxp);
    sample_pass<<<dim3(NB * NH), 256, 0, stream>>>(kf, awp, pyp, pxp, out);
}

// Round 3
// 101.406 us; speedup vs baseline: 2.5715x; 2.5715x over previous
//
#include <hip/hip_runtime.h>

typedef unsigned short u16;
typedef __attribute__((ext_vector_type(8))) short bf16x8;
typedef __attribute__((ext_vector_type(4))) float f32x4;

__device__ __forceinline__ u16 f2bf(float f) {
    unsigned u = __float_as_uint(f);
    unsigned r = (u + 0x7fffu + ((u >> 16) & 1u)) >> 16;
    return (u16)r;
}
__device__ __forceinline__ float bflo(unsigned w) { return __uint_as_float(w << 16); }
__device__ __forceinline__ float bfhi(unsigned w) { return __uint_as_float(w & 0xffff0000u); }

#define NB 8
#define NC 256
#define NK 9
#define NH 64
#define NW 64
#define NP 4096
#define SWZ(o) ((o) ^ (((o) >> 3) & 7))

// ---------------- pass 1: kf16[b][px][c] = bf16(w_refer @ key + b_refer) ----------------
__global__ __launch_bounds__(256) void kf_gemm(const float* __restrict__ key,
                                               const float* __restrict__ w_refer,
                                               const float* __restrict__ b_refer,
                                               u16* __restrict__ kf16)
{
    __shared__ u16 T[128 * 136];           // [px_local][co_local], stride 136 vs 128 (bank spread)
    const int pt  = blockIdx.x;            // 256 pixel tiles (32 per batch)
    const int b   = pt >> 5;
    const int p0  = (pt & 31) << 7;
    const int co0 = blockIdx.y << 7;
    const int lane = threadIdx.x & 63, wid = threadIdx.x >> 6;
    const int wm = wid & 1, wn = wid >> 1;          // wave quadrant: 64co x 64px
    const int fr = lane & 15, kq = (lane >> 4) << 3;

    f32x4 acc[4][4];
    #pragma unroll
    for (int i = 0; i < 4; ++i)
        #pragma unroll
        for (int j = 0; j < 4; ++j) acc[i][j] = (f32x4){0.f, 0.f, 0.f, 0.f};

    for (int ks = 0; ks < 8; ++ks) {
        const int k0 = (ks << 5) + kq;              // this lane's k-octet base
        bf16x8 af[4], bfv[4];
        #pragma unroll
        for (int mi = 0; mi < 4; ++mi) {
            const float* src = &w_refer[(size_t)(co0 + (wm << 6) + (mi << 4) + fr) * NC + k0];
            float4 v0 = *(const float4*)src;
            float4 v1 = *(const float4*)(src + 4);
            bf16x8 a;
            a[0] = (short)f2bf(v0.x); a[1] = (short)f2bf(v0.y);
            a[2] = (short)f2bf(v0.z); a[3] = (short)f2bf(v0.w);
            a[4] = (short)f2bf(v1.x); a[5] = (short)f2bf(v1.y);
            a[6] = (short)f2bf(v1.z); a[7] = (short)f2bf(v1.w);
            af[mi] = a;
        }
        #pragma unroll
        for (int ni = 0; ni < 4; ++ni) {
            const float* src = &key[((size_t)b * NC + k0) * NP + p0 + (wn << 6) + (ni << 4) + fr];
            bf16x8 bv;
            #pragma unroll
            for (int j = 0; j < 8; ++j) bv[j] = (short)f2bf(src[(size_t)j * NP]);
            bfv[ni] = bv;
        }
        #pragma unroll
        for (int mi = 0; mi < 4; ++mi)
            #pragma unroll
            for (int ni = 0; ni < 4; ++ni)
                acc[mi][ni] = __builtin_amdgcn_mfma_f32_16x16x32_bf16(af[mi], bfv[ni], acc[mi][ni], 0, 0, 0);
    }
    // D mapping (m89-verified): col = lane&15 (px), row = (lane>>4)*4 + reg (c_out)
    const int col = lane & 15, rbase = (lane >> 4) << 2;
    #pragma unroll
    for (int mi = 0; mi < 4; ++mi) {
        #pragma unroll
        for (int rr = 0; rr < 4; ++rr) {
            int co_l = (wm << 6) + (mi << 4) + rbase + rr;
            float bias = b_refer[co0 + co_l];
            #pragma unroll
            for (int ni = 0; ni < 4; ++ni) {
                int px_l = (wn << 6) + (ni << 4) + col;
                T[px_l * 136 + co_l] = f2bf(acc[mi][ni][rr] + bias);
            }
        }
    }
    __syncthreads();
    // coalesced store: per instr, 16-lane groups cover one 256B half-record
    #pragma unroll
    for (int j = 0; j < 8; ++j) {
        int px_l = (j << 4) + (wid << 2) + (lane >> 4);
        int ch = (lane & 15) << 3;
        uint4 v = *(const uint4*)&T[px_l * 136 + ch];
        *(uint4*)&kf16[((size_t)b * NP + p0 + px_l) * NC + co0 + ch] = v;
    }
}

// --------- pass 2: heads + softmaxes -> premultiplied bilinear meta --------------
__global__ __launch_bounds__(256) void head_pass(const float* __restrict__ query,
                                                 const float* __restrict__ gumbel,
                                                 const float* __restrict__ w_attn, const float* __restrict__ b_attn,
                                                 const float* __restrict__ w_mask, const float* __restrict__ b_mask,
                                                 const float* __restrict__ w_off,  const float* __restrict__ b_off,
                                                 const int* __restrict__ temp_p,
                                                 float4* __restrict__ wgt, uint2* __restrict__ offs)
{
    __shared__ float Wf[36][256];
    __shared__ float partial[4][36][64];
    const int blk = blockIdx.x;
    const int b = blk >> 6, row = blk & 63;
    const int p0 = row << 6;
    const int t = threadIdx.x;
    const int tx = t & 63, ty = t >> 6;

    for (int ch = t; ch < 2304; ch += 256) {          // 36 rows x 64 float4
        int o = ch >> 6, c4 = (ch & 63) << 2;
        const float* src = (o < 9) ? &w_attn[o * NC + c4]
                       : (o < 18 ? &w_mask[(o - 9) * NC + c4]
                                 : &w_off[(o - 18) * NC + c4]);
        *(float4*)&Wf[o][c4] = *(const float4*)src;
    }
    float q[64];
    {
        const float* qb = &query[((size_t)b * NC + (ty << 6)) * NP + p0 + tx];
        #pragma unroll
        for (int i = 0; i < 64; ++i) q[i] = qb[(size_t)i * NP];
    }
    __syncthreads();
    #pragma unroll 1
    for (int o = 0; o < 36; ++o) {
        const float4* wrow = (const float4*)&Wf[o][ty << 6];
        float s = 0.f;
        #pragma unroll
        for (int c4 = 0; c4 < 16; ++c4) {
            float4 wv = wrow[c4];
            s += wv.x * q[c4 * 4] + wv.y * q[c4 * 4 + 1] + wv.z * q[c4 * 4 + 2] + wv.w * q[c4 * 4 + 3];
        }
        partial[ty][o][tx] = s;
    }
    __syncthreads();
    if (t < 64) {
        const int pxl = t;
        float v[36];
        #pragma unroll
        for (int o = 0; o < 36; ++o)
            v[o] = partial[0][o][pxl] + partial[1][o][pxl] + partial[2][o][pxl] + partial[3][o][pxl];
        int ti = temp_p[0];
        float tempf = (ti >= 1 && ti < (1 << 23)) ? (float)ti : __int_as_float(ti);
        float am[9], hs[9];
        float mx = -1e30f;
        #pragma unroll
        for (int k = 0; k < 9; ++k) {
            am[k] = v[k] + b_attn[k];
            float g = gumbel[((size_t)b * NK + k) * NP + p0 + pxl];
            hs[k] = (v[9 + k] + b_mask[k] + g) / tempf;
            mx = fmaxf(mx, hs[k]);
        }
        float ssum = 0.f;
        #pragma unroll
        for (int k = 0; k < 9; ++k) { hs[k] = __expf(hs[k] - mx); ssum += hs[k]; }
        float inv = 1.f / ssum;
        float lg[9]; float mx2 = -1e30f;
        #pragma unroll
        for (int k = 0; k < 9; ++k) { lg[k] = am[k] * (hs[k] * inv); mx2 = fmaxf(mx2, lg[k]); }
        float s2 = 0.f;
        #pragma unroll
        for (int k = 0; k < 9; ++k) { lg[k] = __expf(lg[k] - mx2); s2 += lg[k]; }
        float inv2 = 1.f / s2;
        #pragma unroll
        for (int k = 0; k < 9; ++k) {
            float a = lg[k] * inv2;
            float pyv = (float)row + (v[18 + k] + b_off[k]);       // dy = off chan k
            float pxv = (float)pxl + (v[19 + k] + b_off[k + 1]);   // dx = off chan k+1 (!)
            float y0f = floorf(pyv), x0f = floorf(pxv);
            float wy = pyv - y0f, wx = pxv - x0f;
            int y0 = (int)y0f, x0 = (int)x0f;
            int y1 = y0 + 1, x1 = x0 + 1;
            float vy0 = (y0 >= 0 && y0 < NH) ? 1.f : 0.f;
            float vy1 = (y1 >= 0 && y1 < NH) ? 1.f : 0.f;
            float vx0 = (x0 >= 0 && x0 < NW) ? 1.f : 0.f;
            float vx1 = (x1 >= 0 && x1 < NW) ? 1.f : 0.f;
            int y0c = min(max(y0, 0), NH - 1), y1c = min(max(y1, 0), NH - 1);
            int x0c = min(max(x0, 0), NW - 1), x1c = min(max(x1, 0), NW - 1);
            unsigned o00 = (unsigned)(y0c * NW + x0c), o01 = (unsigned)(y0c * NW + x1c);
            unsigned o10 = (unsigned)(y1c * NW + x0c), o11 = (unsigned)(y1c * NW + x1c);
            size_t idx = ((size_t)b * NK + k) * NP + p0 + pxl;
            wgt[idx]  = make_float4(a * (1.f - wy) * (1.f - wx) * vy0 * vx0,
                                    a * (1.f - wy) * wx * vy0 * vx1,
                                    a * wy * (1.f - wx) * vy1 * vx0,
                                    a * wy * wx * vy1 * vx1);
            offs[idx] = make_uint2(o00 | (o01 << 16), o10 | (o11 << 16));
        }
    }
}

// --------------- pass 3: LDS-staged bilinear gather + weighted sum over K ----------------
__global__ __launch_bounds__(512) void sample_pass(const u16* __restrict__ kf16,
                                                   const float4* __restrict__ wgt,
                                                   const uint2* __restrict__ offs,
                                                   float* __restrict__ out)
{
    __shared__ u16 P[NP * 8];              // 64KB: swizzled 16B px-records of 8 channels
    const int bid = blockIdx.x;
    const int b = bid & 7, cg = bid >> 3;  // batch = bid%8 -> XCD-batch affinity
    const int c0 = cg << 3;
    const int t = threadIdx.x;

    // stage: record o -> LDS chunk SWZ(o)
    #pragma unroll
    for (int s = 0; s < 8; ++s) {
        int o = (s << 9) + t;
        uint4 v = *(const uint4*)&kf16[((size_t)b * NP + o) * NC + c0];
        *(uint4*)&P[SWZ(o) << 3] = v;
    }
    __syncthreads();

    const float4* wb = wgt  + (size_t)b * NK * NP;
    const uint2*  ob = offs + (size_t)b * NK * NP;
    #pragma unroll 1
    for (int i = 0; i < 8; ++i) {
        int px = (i << 9) + t;
        float acc[8];
        #pragma unroll
        for (int j = 0; j < 8; ++j) acc[j] = 0.f;
        #pragma unroll
        for (int k = 0; k < NK; ++k) {
            float4 wv = wb[k * NP + px];
            uint2 ov  = ob[k * NP + px];
            int   o4[4] = { (int)(ov.x & 0xffffu), (int)(ov.x >> 16),
                            (int)(ov.y & 0xffffu), (int)(ov.y >> 16) };
            float w4[4] = { wv.x, wv.y, wv.z, wv.w };
            #pragma unroll
            for (int cnr = 0; cnr < 4; ++cnr) {
                float wc = w4[cnr];
                uint4 r = *(const uint4*)&P[SWZ(o4[cnr]) << 3];
                acc[0] += wc * bflo(r.x); acc[1] += wc * bfhi(r.x);
                acc[2] += wc * bflo(r.y); acc[3] += wc * bfhi(r.y);
                acc[4] += wc * bflo(r.z); acc[5] += wc * bfhi(r.z);
                acc[6] += wc * bflo(r.w); acc[7] += wc * bfhi(r.w);
            }
        }
        float* op = out + ((size_t)b * NC + c0) * NP + px;
        #pragma unroll
        for (int j = 0; j < 8; ++j) op[(size_t)j * NP] = acc[j];
    }
}

extern "C" void kernel_launch(void* const* d_in, const int* in_sizes, int n_in,
                              void* d_out, int out_size, void* d_ws, size_t ws_size,
                              hipStream_t stream)
{
    const float* query   = (const float*)d_in[0];
    const float* key     = (const float*)d_in[1];
    const float* gumbel  = (const float*)d_in[2];
    const float* w_refer = (const float*)d_in[3];
    const float* b_refer = (const float*)d_in[4];
    const float* w_attn  = (const float*)d_in[5];
    const float* b_attn  = (const float*)d_in[6];
    const float* w_mask  = (const float*)d_in[7];
    const float* b_mask  = (const float*)d_in[8];
    const float* w_off   = (const float*)d_in[9];
    const float* b_off   = (const float*)d_in[10];
    const int*   temp    = (const int*)d_in[11];
    float* out = (float*)d_out;

    u16*    kf16 = (u16*)d_ws;                                         // 16.78 MB
    float4* wgt  = (float4*)((char*)d_ws + (size_t)NB * NP * NC * 2);  // 4.72 MB
    uint2*  offs = (uint2*)((char*)wgt + (size_t)NB * NK * NP * 16);   // 2.36 MB

    kf_gemm<<<dim3(256, 2), 256, 0, stream>>>(key, w_refer, b_refer, kf16);
    head_pass<<<dim3(NB * NH), 256, 0, stream>>>(query, gumbel, w_attn, b_attn,
                                                 w_mask, b_mask, w_off, b_off, temp,
                                                 wgt, offs);
    sample_pass<<<256, 512, 0, stream>>>(kf16, wgt, offs, out);
}

// Round 4
// 84.473 us; speedup vs baseline: 3.0869x; 1.2005x over previous
//
#include <hip/hip_runtime.h>

typedef unsigned short u16;
typedef __attribute__((ext_vector_type(8))) short bf16x8;
typedef __attribute__((ext_vector_type(4))) float f32x4;

__device__ __forceinline__ u16 f2bf(float f) {
    unsigned u = __float_as_uint(f);
    unsigned r = (u + 0x7fffu + ((u >> 16) & 1u)) >> 16;
    return (u16)r;
}
__device__ __forceinline__ float bf2f(u16 h) {
    union { unsigned u; float f; } x; x.u = ((unsigned)h) << 16; return x.f;
}

#define NB 8
#define NC 256
#define NK 9
#define NH 64
#define NW 64
#define NP 4096
#define BAND 320            // 5 rows x 64 px sampling band
#define SB_STRIDE 328       // u16 stride: 656B rows -> 16B aligned, 2-way (free) bank alias

// ---------------- pass 1: kf16[b][c][px] = bf16(w_refer @ key + b_refer) ----------------
__global__ __launch_bounds__(256) void kf_gemm(const float* __restrict__ key,
                                               const float* __restrict__ w_refer,
                                               const float* __restrict__ b_refer,
                                               u16* __restrict__ kf16)
{
    const int pt  = blockIdx.x;            // 256 pixel tiles (32 per batch)
    const int b   = pt >> 5;
    const int p0  = (pt & 31) << 7;
    const int co0 = blockIdx.y << 7;
    const int lane = threadIdx.x & 63, wid = threadIdx.x >> 6;
    const int wm = wid & 1, wn = wid >> 1;          // wave quadrant: 64co x 64px
    const int fr = lane & 15, kq = (lane >> 4) << 3;

    f32x4 acc[4][4];
    #pragma unroll
    for (int i = 0; i < 4; ++i)
        #pragma unroll
        for (int j = 0; j < 4; ++j) acc[i][j] = (f32x4){0.f, 0.f, 0.f, 0.f};

    for (int ks = 0; ks < 8; ++ks) {
        const int k0 = (ks << 5) + kq;
        bf16x8 af[4], bfv[4];
        #pragma unroll
        for (int mi = 0; mi < 4; ++mi) {
            const float* src = &w_refer[(size_t)(co0 + (wm << 6) + (mi << 4) + fr) * NC + k0];
            float4 v0 = *(const float4*)src;
            float4 v1 = *(const float4*)(src + 4);
            bf16x8 a;
            a[0] = (short)f2bf(v0.x); a[1] = (short)f2bf(v0.y);
            a[2] = (short)f2bf(v0.z); a[3] = (short)f2bf(v0.w);
            a[4] = (short)f2bf(v1.x); a[5] = (short)f2bf(v1.y);
            a[6] = (short)f2bf(v1.z); a[7] = (short)f2bf(v1.w);
            af[mi] = a;
        }
        #pragma unroll
        for (int ni = 0; ni < 4; ++ni) {
            const float* src = &key[((size_t)b * NC + k0) * NP + p0 + (wn << 6) + (ni << 4) + fr];
            bf16x8 bv;
            #pragma unroll
            for (int j = 0; j < 8; ++j) bv[j] = (short)f2bf(src[(size_t)j * NP]);
            bfv[ni] = bv;
        }
        #pragma unroll
        for (int mi = 0; mi < 4; ++mi)
            #pragma unroll
            for (int ni = 0; ni < 4; ++ni)
                acc[mi][ni] = __builtin_amdgcn_mfma_f32_16x16x32_bf16(af[mi], bfv[ni], acc[mi][ni], 0, 0, 0);
    }
    // D mapping: col = lane&15 (px), row = (lane>>4)*4 + reg (c_out). Direct u16 stores.
    const int col = lane & 15, rbase = (lane >> 4) << 2;
    #pragma unroll
    for (int mi = 0; mi < 4; ++mi) {
        #pragma unroll
        for (int rr = 0; rr < 4; ++rr) {
            int co = co0 + (wm << 6) + (mi << 4) + rbase + rr;
            float bias = b_refer[co];
            u16* dst = &kf16[((size_t)b * NC + co) * NP + p0 + (wn << 6) + col];
            #pragma unroll
            for (int ni = 0; ni < 4; ++ni)
                dst[ni << 4] = f2bf(acc[mi][ni][rr] + bias);
        }
    }
}

// --------- pass 2: heads + softmaxes -> premultiplied bilinear meta --------------
__global__ __launch_bounds__(256) void head_pass(const float* __restrict__ query,
                                                 const float* __restrict__ gumbel,
                                                 const float* __restrict__ w_attn, const float* __restrict__ b_attn,
                                                 const float* __restrict__ w_mask, const float* __restrict__ b_mask,
                                                 const float* __restrict__ w_off,  const float* __restrict__ b_off,
                                                 const int* __restrict__ temp_p,
                                                 float4* __restrict__ wgt, uint2* __restrict__ offs)
{
    __shared__ float Wf[36][256];
    __shared__ float partial[4][36][64];
    const int blk = blockIdx.x;
    const int b = blk >> 6, row = blk & 63;
    const int p0 = row << 6;
    const int t = threadIdx.x;
    const int tx = t & 63, ty = t >> 6;

    for (int ch = t; ch < 2304; ch += 256) {          // 36 rows x 64 float4
        int o = ch >> 6, c4 = (ch & 63) << 2;
        const float* src = (o < 9) ? &w_attn[o * NC + c4]
                       : (o < 18 ? &w_mask[(o - 9) * NC + c4]
                                 : &w_off[(o - 18) * NC + c4]);
        *(float4*)&Wf[o][c4] = *(const float4*)src;
    }
    float q[64];
    {
        const float* qb = &query[((size_t)b * NC + (ty << 6)) * NP + p0 + tx];
        #pragma unroll
        for (int i = 0; i < 64; ++i) q[i] = qb[(size_t)i * NP];
    }
    __syncthreads();
    #pragma unroll 1
    for (int o = 0; o < 36; ++o) {
        const float4* wrow = (const float4*)&Wf[o][ty << 6];
        float s = 0.f;
        #pragma unroll
        for (int c4 = 0; c4 < 16; ++c4) {
            float4 wv = wrow[c4];
            s += wv.x * q[c4 * 4] + wv.y * q[c4 * 4 + 1] + wv.z * q[c4 * 4 + 2] + wv.w * q[c4 * 4 + 3];
        }
        partial[ty][o][tx] = s;
    }
    __syncthreads();
    if (t < 64) {
        const int pxl = t;
        float v[36];
        #pragma unroll
        for (int o = 0; o < 36; ++o)
            v[o] = partial[0][o][pxl] + partial[1][o][pxl] + partial[2][o][pxl] + partial[3][o][pxl];
        int ti = temp_p[0];
        float tempf = (ti >= 1 && ti < (1 << 23)) ? (float)ti : __int_as_float(ti);
        float am[9], hs[9];
        float mx = -1e30f;
        #pragma unroll
        for (int k = 0; k < 9; ++k) {
            am[k] = v[k] + b_attn[k];
            float g = gumbel[((size_t)b * NK + k) * NP + p0 + pxl];
            hs[k] = (v[9 + k] + b_mask[k] + g) / tempf;
            mx = fmaxf(mx, hs[k]);
        }
        float ssum = 0.f;
        #pragma unroll
        for (int k = 0; k < 9; ++k) { hs[k] = __expf(hs[k] - mx); ssum += hs[k]; }
        float inv = 1.f / ssum;
        float lg[9]; float mx2 = -1e30f;
        #pragma unroll
        for (int k = 0; k < 9; ++k) { lg[k] = am[k] * (hs[k] * inv); mx2 = fmaxf(mx2, lg[k]); }
        float s2 = 0.f;
        #pragma unroll
        for (int k = 0; k < 9; ++k) { lg[k] = __expf(lg[k] - mx2); s2 += lg[k]; }
        float inv2 = 1.f / s2;
        #pragma unroll
        for (int k = 0; k < 9; ++k) {
            float a = lg[k] * inv2;
            float pyv = (float)row + (v[18 + k] + b_off[k]);       // dy = off chan k
            float pxv = (float)pxl + (v[19 + k] + b_off[k + 1]);   // dx = off chan k+1 (!)
            float y0f = floorf(pyv), x0f = floorf(pxv);
            float wy = pyv - y0f, wx = pxv - x0f;
            int y0 = (int)y0f, x0 = (int)x0f;
            int y1 = y0 + 1, x1 = x0 + 1;
            float vy0 = (y0 >= 0 && y0 < NH) ? 1.f : 0.f;
            float vy1 = (y1 >= 0 && y1 < NH) ? 1.f : 0.f;
            float vx0 = (x0 >= 0 && x0 < NW) ? 1.f : 0.f;
            float vx1 = (x1 >= 0 && x1 < NW) ? 1.f : 0.f;
            int y0c = min(max(y0, 0), NH - 1), y1c = min(max(y1, 0), NH - 1);
            int x0c = min(max(x0, 0), NW - 1), x1c = min(max(x1, 0), NW - 1);
            unsigned o00 = (unsigned)(y0c * NW + x0c), o01 = (unsigned)(y0c * NW + x1c);
            unsigned o10 = (unsigned)(y1c * NW + x0c), o11 = (unsigned)(y1c * NW + x1c);
            size_t idx = ((size_t)b * NK + k) * NP + p0 + pxl;
            wgt[idx]  = make_float4(a * (1.f - wy) * (1.f - wx) * vy0 * vx0,
                                    a * (1.f - wy) * wx * vy0 * vx1,
                                    a * wy * (1.f - wx) * vy1 * vx0,
                                    a * wy * wx * vy1 * vx1);
            offs[idx] = make_uint2(o00 | (o01 << 16), o10 | (o11 << 16));
        }
    }
}

// ------- pass 3: banded scatter-GEMM: out[c][px] = kf16[c][band] @ S[band][px] -----------
__global__ __launch_bounds__(512, 1) void sample_pass(const u16* __restrict__ kf16,
                                                      const float4* __restrict__ wgt,
                                                      const uint2* __restrict__ offs,
                                                      float* __restrict__ out)
{
    __shared__ float Sf[64][BAND];                 // 80 KB  f32 scatter accumulator
    __shared__ u16  Sb[64][SB_STRIDE];             // 41 KB  bf16 packed B operand
    __shared__ int  esc_cnt;
    __shared__ u16  esc_px[2304];
    __shared__ u16  esc_o[2304];
    __shared__ float esc_w[2304];

    const int bid = blockIdx.x;
    const int b = bid & 7, row = bid >> 3;         // b = bid%8 -> XCD/L2 batch affinity
    const int t = threadIdx.x;
    const int ylo = min(max(row - 2, 0), NH - 5);
    const int base = ylo << 6;

    // --- zero S ---
    #pragma unroll
    for (int i = 0; i < 10; ++i)
        ((float4*)Sf)[t + (i << 9)] = (float4){0.f, 0.f, 0.f, 0.f};
    if (t == 0) esc_cnt = 0;
    __syncthreads();

    // --- scatter 36 weighted corners per px into S (f32 atomics; collisions exact) ---
    {
        const int px = t & 63, kg = t >> 6;
        const int nk = (kg == 0) ? 2 : 1;
        for (int s = 0; s < nk; ++s) {
            int k = (s == 0) ? kg : 8;
            size_t idx = ((size_t)b * NK + k) * NP + (row << 6) + px;
            float4 wv = wgt[idx];
            uint2 ov  = offs[idx];
            int   o4[4] = { (int)(ov.x & 0xffffu), (int)(ov.x >> 16),
                            (int)(ov.y & 0xffffu), (int)(ov.y >> 16) };
            float w4[4] = { wv.x, wv.y, wv.z, wv.w };
            #pragma unroll
            for (int c = 0; c < 4; ++c) {
                int u = o4[c] - base;
                if ((unsigned)u < (unsigned)BAND) {
                    atomicAdd(&Sf[px][u], w4[c]);
                } else {
                    int e = atomicAdd(&esc_cnt, 1);
                    esc_px[e] = (u16)px; esc_o[e] = (u16)o4[c]; esc_w[e] = w4[c];
                }
            }
        }
    }
    __syncthreads();

    // --- pack S -> bf16 ---
    for (int i = t; i < 64 * 40; i += 512) {       // 40 octets per px row
        int px = i / 40, j = (i % 40) << 3;
        float4 a = *(const float4*)&Sf[px][j];
        float4 c = *(const float4*)&Sf[px][j + 4];
        bf16x8 r;
        r[0] = (short)f2bf(a.x); r[1] = (short)f2bf(a.y);
        r[2] = (short)f2bf(a.z); r[3] = (short)f2bf(a.w);
        r[4] = (short)f2bf(c.x); r[5] = (short)f2bf(c.y);
        r[6] = (short)f2bf(c.z); r[7] = (short)f2bf(c.w);
        *(bf16x8*)&Sb[px][j] = r;
    }
    __syncthreads();

    // --- MFMA: 8 waves, wave w -> c rows [w*32, w*32+32), all 64 px, K = 320 ---
    const int lane = t & 63, wid = t >> 6;
    const int fr = lane & 15, kq = (lane >> 4) << 3;
    const int c0 = wid << 5;
    f32x4 acc[2][4];
    #pragma unroll
    for (int i = 0; i < 2; ++i)
        #pragma unroll
        for (int j = 0; j < 4; ++j) acc[i][j] = (f32x4){0.f, 0.f, 0.f, 0.f};

    const u16* kfb = kf16 + (size_t)b * NC * NP + base;
    #pragma unroll
    for (int step = 0; step < 10; ++step) {
        const int u0 = step << 5;
        bf16x8 af[2], bfv[4];
        #pragma unroll
        for (int mi = 0; mi < 2; ++mi)
            af[mi] = *(const bf16x8*)&kfb[(size_t)(c0 + (mi << 4) + fr) * NP + u0 + kq];
        #pragma unroll
        for (int ni = 0; ni < 4; ++ni)
            bfv[ni] = *(const bf16x8*)&Sb[(ni << 4) + fr][u0 + kq];
        #pragma unroll
        for (int mi = 0; mi < 2; ++mi)
            #pragma unroll
            for (int ni = 0; ni < 4; ++ni)
                acc[mi][ni] = __builtin_amdgcn_mfma_f32_16x16x32_bf16(af[mi], bfv[ni], acc[mi][ni], 0, 0, 0);
    }

    // --- store (block-exclusive out region) ---
    const int col = lane & 15, rbase = (lane >> 4) << 2;
    float* ob = out + (size_t)b * NC * NP + (row << 6);
    #pragma unroll
    for (int mi = 0; mi < 2; ++mi) {
        #pragma unroll
        for (int rr = 0; rr < 4; ++rr) {
            int c = c0 + (mi << 4) + rbase + rr;
            #pragma unroll
            for (int ni = 0; ni < 4; ++ni)
                ob[(size_t)c * NP + (ni << 4) + col] = acc[mi][ni][rr];
        }
    }

    // --- rare out-of-band corners (exactness fallback; empty in practice) ---
    __syncthreads();
    int ec = esc_cnt;
    if (ec > 0) {
        for (int e = t >> 8; e < ec; e += 2) {
            int c = t & 255;
            int px = esc_px[e], o = esc_o[e];
            float w = esc_w[e];
            float* dst = &ob[(size_t)c * NP + px];
            *dst += w * bf2f(kf16[((size_t)b * NC + c) * NP + o]);
        }
    }
}

extern "C" void kernel_launch(void* const* d_in, const int* in_sizes, int n_in,
                              void* d_out, int out_size, void* d_ws, size_t ws_size,
                              hipStream_t stream)
{
    const float* query   = (const float*)d_in[0];
    const float* key     = (const float*)d_in[1];
    const float* gumbel  = (const float*)d_in[2];
    const float* w_refer = (const float*)d_in[3];
    const float* b_refer = (const float*)d_in[4];
    const float* w_attn  = (const float*)d_in[5];
    const float* b_attn  = (const float*)d_in[6];
    const float* w_mask  = (const float*)d_in[7];
    const float* b_mask  = (const float*)d_in[8];
    const float* w_off   = (const float*)d_in[9];
    const float* b_off   = (const float*)d_in[10];
    const int*   temp    = (const int*)d_in[11];
    float* out = (float*)d_out;

    u16*    kf16 = (u16*)d_ws;                                         // 16.78 MB
    float4* wgt  = (float4*)((char*)d_ws + (size_t)NB * NP * NC * 2);  // 4.72 MB
    uint2*  offs = (uint2*)((char*)wgt + (size_t)NB * NK * NP * 16);   // 2.36 MB

    kf_gemm<<<dim3(256, 2), 256, 0, stream>>>(key, w_refer, b_refer, kf16);
    head_pass<<<dim3(NB * NH), 256, 0, stream>>>(query, gumbel, w_attn, b_attn,
                                                 w_mask, b_mask, w_off, b_off, temp,
                                                 wgt, offs);
    sample_pass<<<NB * NH, 512, 0, stream>>>(kf16, wgt, offs, out);
}

// Round 5
// 65.375 us; speedup vs baseline: 3.9887x; 1.2921x over previous
//
#include <hip/hip_runtime.h>

typedef unsigned short u16;
typedef __attribute__((ext_vector_type(8))) short bf16x8;
typedef __attribute__((ext_vector_type(4))) float f32x4;

__device__ __forceinline__ u16 f2bf(float f) {
    unsigned u = __float_as_uint(f);
    unsigned r = (u + 0x7fffu + ((u >> 16) & 1u)) >> 16;
    return (u16)r;
}
__device__ __forceinline__ float bf2f(u16 h) {
    union { unsigned u; float f; } x; x.u = ((unsigned)h) << 16; return x.f;
}

#define NB 8
#define NC 256
#define NK 9
#define NH 64
#define NW 64
#define NP 4096
#define BAND 320            // 5 rows x 64 px sampling band (|dy| < 2 guaranteed-ish; escapes exact)
#define SB_STRIDE 328       // u16 stride for in-place bf16 B tile: 656B rows, 2-way (free) alias

// ---------------- pass 1: kf16[b][c][px] = bf16(w_refer @ key + b_refer) ----------------
__global__ __launch_bounds__(256) void kf_gemm(const float* __restrict__ key,
                                               const float* __restrict__ w_refer,
                                               const float* __restrict__ b_refer,
                                               u16* __restrict__ kf16)
{
    const int pt  = blockIdx.x;            // 256 pixel tiles (32 per batch)
    const int b   = pt >> 5;
    const int p0  = (pt & 31) << 7;
    const int co0 = blockIdx.y << 7;
    const int lane = threadIdx.x & 63, wid = threadIdx.x >> 6;
    const int wm = wid & 1, wn = wid >> 1;          // wave quadrant: 64co x 64px
    const int fr = lane & 15, kq = (lane >> 4) << 3;

    f32x4 acc[4][4];
    #pragma unroll
    for (int i = 0; i < 4; ++i)
        #pragma unroll
        for (int j = 0; j < 4; ++j) acc[i][j] = (f32x4){0.f, 0.f, 0.f, 0.f};

    for (int ks = 0; ks < 8; ++ks) {
        const int k0 = (ks << 5) + kq;
        bf16x8 af[4], bfv[4];
        #pragma unroll
        for (int mi = 0; mi < 4; ++mi) {
            const float* src = &w_refer[(size_t)(co0 + (wm << 6) + (mi << 4) + fr) * NC + k0];
            float4 v0 = *(const float4*)src;
            float4 v1 = *(const float4*)(src + 4);
            bf16x8 a;
            a[0] = (short)f2bf(v0.x); a[1] = (short)f2bf(v0.y);
            a[2] = (short)f2bf(v0.z); a[3] = (short)f2bf(v0.w);
            a[4] = (short)f2bf(v1.x); a[5] = (short)f2bf(v1.y);
            a[6] = (short)f2bf(v1.z); a[7] = (short)f2bf(v1.w);
            af[mi] = a;
        }
        #pragma unroll
        for (int ni = 0; ni < 4; ++ni) {
            const float* src = &key[((size_t)b * NC + k0) * NP + p0 + (wn << 6) + (ni << 4) + fr];
            bf16x8 bv;
            #pragma unroll
            for (int j = 0; j < 8; ++j) bv[j] = (short)f2bf(src[(size_t)j * NP]);
            bfv[ni] = bv;
        }
        #pragma unroll
        for (int mi = 0; mi < 4; ++mi)
            #pragma unroll
            for (int ni = 0; ni < 4; ++ni)
                acc[mi][ni] = __builtin_amdgcn_mfma_f32_16x16x32_bf16(af[mi], bfv[ni], acc[mi][ni], 0, 0, 0);
    }
    const int col = lane & 15, rbase = (lane >> 4) << 2;
    #pragma unroll
    for (int mi = 0; mi < 4; ++mi) {
        #pragma unroll
        for (int rr = 0; rr < 4; ++rr) {
            int co = co0 + (wm << 6) + (mi << 4) + rbase + rr;
            float bias = b_refer[co];
            u16* dst = &kf16[((size_t)b * NC + co) * NP + p0 + (wn << 6) + col];
            #pragma unroll
            for (int ni = 0; ni < 4; ++ni)
                dst[ni << 4] = f2bf(acc[mi][ni][rr] + bias);
        }
    }
}

// ---------- pass 2a: hd[36][b*px] = heads(query) via MFMA (biases folded) ----------
__global__ __launch_bounds__(256) void hd_gemm(const float* __restrict__ query,
                                               const float* __restrict__ w_attn, const float* __restrict__ b_attn,
                                               const float* __restrict__ w_mask, const float* __restrict__ b_mask,
                                               const float* __restrict__ w_off,  const float* __restrict__ b_off,
                                               float* __restrict__ hd)
{
    __shared__ u16 A[48][264];     // bf16 head weights, rows 36..47 zero; 528B stride
    const int pt = blockIdx.x;     // 256 tiles of 128 px
    const int b  = pt >> 5;
    const int p0 = (pt & 31) << 7;
    const int t = threadIdx.x;
    const int lane = t & 63, wn = t >> 6;           // 4 waves, 32 px each
    const int fr = lane & 15, kq = (lane >> 4) << 3;

    for (int i = t; i < 1152; i += 256) {           // 36 rows x 32 octets
        int o = i >> 5, c = (i & 31) << 3;
        const float* src = (o < 9) ? &w_attn[o * NC + c]
                       : (o < 18 ? &w_mask[(o - 9) * NC + c]
                                 : &w_off[(o - 18) * NC + c]);
        float4 v0 = *(const float4*)src;
        float4 v1 = *(const float4*)(src + 4);
        bf16x8 a;
        a[0] = (short)f2bf(v0.x); a[1] = (short)f2bf(v0.y);
        a[2] = (short)f2bf(v0.z); a[3] = (short)f2bf(v0.w);
        a[4] = (short)f2bf(v1.x); a[5] = (short)f2bf(v1.y);
        a[6] = (short)f2bf(v1.z); a[7] = (short)f2bf(v1.w);
        *(bf16x8*)&A[o][c] = a;
    }
    for (int i = t; i < 384; i += 256) {            // zero pad rows 36..47
        bf16x8 z = {0,0,0,0,0,0,0,0};
        *(bf16x8*)&A[36 + (i >> 5)][(i & 31) << 3] = z;
    }
    __syncthreads();

    f32x4 acc[3][2];
    #pragma unroll
    for (int i = 0; i < 3; ++i)
        #pragma unroll
        for (int j = 0; j < 2; ++j) acc[i][j] = (f32x4){0.f, 0.f, 0.f, 0.f};

    for (int ks = 0; ks < 8; ++ks) {
        const int k0 = (ks << 5) + kq;
        bf16x8 af[3], bfv[2];
        #pragma unroll
        for (int mi = 0; mi < 3; ++mi)
            af[mi] = *(const bf16x8*)&A[(mi << 4) + fr][k0];
        #pragma unroll
        for (int ni = 0; ni < 2; ++ni) {
            const float* src = &query[((size_t)b * NC + k0) * NP + p0 + (wn << 5) + (ni << 4) + fr];
            bf16x8 bv;
            #pragma unroll
            for (int j = 0; j < 8; ++j) bv[j] = (short)f2bf(src[(size_t)j * NP]);
            bfv[ni] = bv;
        }
        #pragma unroll
        for (int mi = 0; mi < 3; ++mi)
            #pragma unroll
            for (int ni = 0; ni < 2; ++ni)
                acc[mi][ni] = __builtin_amdgcn_mfma_f32_16x16x32_bf16(af[mi], bfv[ni], acc[mi][ni], 0, 0, 0);
    }
    const int col = lane & 15, rbase = (lane >> 4) << 2;
    #pragma unroll
    for (int mi = 0; mi < 3; ++mi) {
        #pragma unroll
        for (int rr = 0; rr < 4; ++rr) {
            int co = (mi << 4) + rbase + rr;
            if (co < 36) {
                float bias = (co < 9) ? b_attn[co] : (co < 18) ? b_mask[co - 9] : b_off[co - 18];
                #pragma unroll
                for (int ni = 0; ni < 2; ++ni)
                    hd[(size_t)co * (NB * NP) + (size_t)b * NP + p0 + (wn << 5) + (ni << 4) + col]
                        = acc[mi][ni][rr] + bias;
            }
        }
    }
}

// ---------- pass 2b: elementwise softmaxes + premultiplied bilinear meta ----------
__global__ __launch_bounds__(128) void meta_pass(const float* __restrict__ hd,
                                                 const float* __restrict__ gumbel,
                                                 const int* __restrict__ temp_p,
                                                 float4* __restrict__ wgt, uint2* __restrict__ offs)
{
    const int gp = blockIdx.x * 128 + threadIdx.x;   // 0..32767
    const int b = gp >> 12, pxl = gp & 4095;
    const int row = pxl >> 6, xcol = pxl & 63;

    float v[36];
    #pragma unroll
    for (int o = 0; o < 36; ++o) v[o] = hd[(size_t)o * (NB * NP) + gp];

    int ti = temp_p[0];
    float tempf = (ti >= 1 && ti < (1 << 23)) ? (float)ti : __int_as_float(ti);
    float am[9], hs[9];
    float mx = -1e30f;
    #pragma unroll
    for (int k = 0; k < 9; ++k) {
        am[k] = v[k];
        float g = gumbel[((size_t)b * NK + k) * NP + pxl];
        hs[k] = (v[9 + k] + g) / tempf;
        mx = fmaxf(mx, hs[k]);
    }
    float ssum = 0.f;
    #pragma unroll
    for (int k = 0; k < 9; ++k) { hs[k] = __expf(hs[k] - mx); ssum += hs[k]; }
    float inv = 1.f / ssum;
    float lg[9]; float mx2 = -1e30f;
    #pragma unroll
    for (int k = 0; k < 9; ++k) { lg[k] = am[k] * (hs[k] * inv); mx2 = fmaxf(mx2, lg[k]); }
    float s2 = 0.f;
    #pragma unroll
    for (int k = 0; k < 9; ++k) { lg[k] = __expf(lg[k] - mx2); s2 += lg[k]; }
    float inv2 = 1.f / s2;
    #pragma unroll
    for (int k = 0; k < 9; ++k) {
        float a = lg[k] * inv2;
        float pyv = (float)row  + v[18 + k];       // dy = off chan k   (bias folded)
        float pxv = (float)xcol + v[19 + k];       // dx = off chan k+1 (!)
        float y0f = floorf(pyv), x0f = floorf(pxv);
        float wy = pyv - y0f, wx = pxv - x0f;
        int y0 = (int)y0f, x0 = (int)x0f;
        int y1 = y0 + 1, x1 = x0 + 1;
        float vy0 = (y0 >= 0 && y0 < NH) ? 1.f : 0.f;
        float vy1 = (y1 >= 0 && y1 < NH) ? 1.f : 0.f;
        float vx0 = (x0 >= 0 && x0 < NW) ? 1.f : 0.f;
        float vx1 = (x1 >= 0 && x1 < NW) ? 1.f : 0.f;
        int y0c = min(max(y0, 0), NH - 1), y1c = min(max(y1, 0), NH - 1);
        int x0c = min(max(x0, 0), NW - 1), x1c = min(max(x1, 0), NW - 1);
        unsigned o00 = (unsigned)(y0c * NW + x0c), o01 = (unsigned)(y0c * NW + x1c);
        unsigned o10 = (unsigned)(y1c * NW + x0c), o11 = (unsigned)(y1c * NW + x1c);
        size_t idx = ((size_t)b * NK + k) * NP + pxl;
        wgt[idx]  = make_float4(a * (1.f - wy) * (1.f - wx) * vy0 * vx0,
                                a * (1.f - wy) * wx * vy0 * vx1,
                                a * wy * (1.f - wx) * vy1 * vx0,
                                a * wy * wx * vy1 * vx1);
        offs[idx] = make_uint2(o00 | (o01 << 16), o10 | (o11 << 16));
    }
}

// ------- pass 3: banded scatter-GEMM: out[c][px] = kf16[c][band] @ S[band][px] -----------
__global__ __launch_bounds__(512, 4) void sample_pass(const u16* __restrict__ kf16,
                                                      const float4* __restrict__ wgt,
                                                      const uint2* __restrict__ offs,
                                                      float* __restrict__ out)
{
    __shared__ float Sf[64][BAND];                 // exactly 80 KB -> 2 blocks/CU

    const int bid = blockIdx.x;
    const int b = bid & 7, row = bid >> 3;         // b = bid%8 -> XCD/L2 batch affinity
    const int t = threadIdx.x;
    const int lane = t & 63, wid = t >> 6;
    const int fr = lane & 15, kq = (lane >> 4) << 3;
    const int c0 = wid << 5;
    const int ylo = min(max(row - 2, 0), NH - 5);
    const int base = ylo << 6;
    const u16* kfb = kf16 + (size_t)b * NC * NP + base;

    // --- prefetch meta (consumed in scatter) ---
    const int px = t & 63, kg = t >> 6;
    size_t idx0 = ((size_t)b * NK + kg) * NP + (row << 6) + px;
    float4 wv0 = wgt[idx0];
    uint2  ov0 = offs[idx0];
    float4 wv1 = make_float4(0.f, 0.f, 0.f, 0.f);
    uint2  ov1 = make_uint2(0u, 0u);
    if (kg == 0) {
        size_t idx1 = ((size_t)b * NK + 8) * NP + (row << 6) + px;
        wv1 = wgt[idx1]; ov1 = offs[idx1];
    }
    // --- prefetch A fragments, 4 K-steps deep ---
    bf16x8 apre[4][2];
    #pragma unroll
    for (int s = 0; s < 4; ++s)
        #pragma unroll
        for (int mi = 0; mi < 2; ++mi)
            apre[s][mi] = *(const bf16x8*)&kfb[(size_t)(c0 + (mi << 4) + fr) * NP + (s << 5) + kq];

    // --- zero S ---
    #pragma unroll
    for (int i = 0; i < 10; ++i)
        ((float4*)Sf)[t + (i << 9)] = (float4){0.f, 0.f, 0.f, 0.f};
    __syncthreads();

    // --- scatter 36 weighted corners per px (f32 atomics; escapes -> flag) ---
    bool esc = false;
    {
        #pragma unroll
        for (int s = 0; s < 2; ++s) {
            if (s == 1 && kg != 0) break;
            float4 wv = s ? wv1 : wv0;
            uint2  ov = s ? ov1 : ov0;
            int   o4[4] = { (int)(ov.x & 0xffffu), (int)(ov.x >> 16),
                            (int)(ov.y & 0xffffu), (int)(ov.y >> 16) };
            float w4[4] = { wv.x, wv.y, wv.z, wv.w };
            #pragma unroll
            for (int c = 0; c < 4; ++c) {
                int u = o4[c] - base;
                if ((unsigned)u < (unsigned)BAND) atomicAdd(&Sf[px][u], w4[c]);
                else esc = true;
            }
        }
    }
    __syncthreads();

    // --- in-place pack S -> bf16 (read regs, sync, write) ---
    u16* Sb = (u16*)&Sf[0][0];                     // stride SB_STRIDE u16 (656B rows)
    bf16x8 pk[5];
    int pp[5], pj[5];
    #pragma unroll
    for (int r = 0; r < 5; ++r) {
        int i = t + (r << 9);
        int p = i / 40, j = (i % 40) << 3;
        float4 a = *(const float4*)&Sf[p][j];
        float4 c = *(const float4*)&Sf[p][j + 4];
        bf16x8 q;
        q[0] = (short)f2bf(a.x); q[1] = (short)f2bf(a.y);
        q[2] = (short)f2bf(a.z); q[3] = (short)f2bf(a.w);
        q[4] = (short)f2bf(c.x); q[5] = (short)f2bf(c.y);
        q[6] = (short)f2bf(c.z); q[7] = (short)f2bf(c.w);
        pk[r] = q; pp[r] = p; pj[r] = j;
    }
    __syncthreads();
    #pragma unroll
    for (int r = 0; r < 5; ++r)
        *(bf16x8*)&Sb[pp[r] * SB_STRIDE + pj[r]] = pk[r];
    __syncthreads();

    // --- MFMA: wave w -> c rows [w*32, w*32+32), 64 px, K = 320; A pipelined 4 deep ---
    f32x4 acc[2][4];
    #pragma unroll
    for (int i = 0; i < 2; ++i)
        #pragma unroll
        for (int j = 0; j < 4; ++j) acc[i][j] = (f32x4){0.f, 0.f, 0.f, 0.f};

    #pragma unroll
    for (int step = 0; step < 10; ++step) {
        bf16x8 a0 = apre[step & 3][0], a1 = apre[step & 3][1];
        if (step + 4 < 10) {
            #pragma unroll
            for (int mi = 0; mi < 2; ++mi)
                apre[step & 3][mi] =
                    *(const bf16x8*)&kfb[(size_t)(c0 + (mi << 4) + fr) * NP + ((step + 4) << 5) + kq];
        }
        bf16x8 bfv[4];
        #pragma unroll
        for (int ni = 0; ni < 4; ++ni)
            bfv[ni] = *(const bf16x8*)&Sb[((ni << 4) + fr) * SB_STRIDE + (step << 5) + kq];
        #pragma unroll
        for (int ni = 0; ni < 4; ++ni) {
            acc[0][ni] = __builtin_amdgcn_mfma_f32_16x16x32_bf16(a0, bfv[ni], acc[0][ni], 0, 0, 0);
            acc[1][ni] = __builtin_amdgcn_mfma_f32_16x16x32_bf16(a1, bfv[ni], acc[1][ni], 0, 0, 0);
        }
    }

    // --- store (block-exclusive out region) ---
    const int col = lane & 15, rbase = (lane >> 4) << 2;
    float* ob = out + (size_t)b * NC * NP + (row << 6);
    #pragma unroll
    for (int mi = 0; mi < 2; ++mi) {
        #pragma unroll
        for (int rr = 0; rr < 4; ++rr) {
            int c = c0 + (mi << 4) + rbase + rr;
            #pragma unroll
            for (int ni = 0; ni < 4; ++ni)
                ob[(size_t)c * NP + (ni << 4) + col] = acc[mi][ni][rr];
        }
    }

    // --- rare out-of-band corners (exact fallback; ~never executes) ---
    __syncthreads();
    if (esc) {
        for (int s = 0; s < (kg == 0 ? 2 : 1); ++s) {
            int k = s ? 8 : kg;
            size_t idx = ((size_t)b * NK + k) * NP + (row << 6) + px;
            float4 wv = wgt[idx];
            uint2  ov = offs[idx];
            int   o4[4] = { (int)(ov.x & 0xffffu), (int)(ov.x >> 16),
                            (int)(ov.y & 0xffffu), (int)(ov.y >> 16) };
            float w4[4] = { wv.x, wv.y, wv.z, wv.w };
            for (int c = 0; c < 4; ++c) {
                int u = o4[c] - base;
                if ((unsigned)u >= (unsigned)BAND) {
                    for (int cc = 0; cc < NC; ++cc)
                        atomicAdd(&ob[(size_t)cc * NP + px],
                                  w4[c] * bf2f(kf16[((size_t)b * NC + cc) * NP + o4[c]]));
                }
            }
        }
    }
}

extern "C" void kernel_launch(void* const* d_in, const int* in_sizes, int n_in,
                              void* d_out, int out_size, void* d_ws, size_t ws_size,
                              hipStream_t stream)
{
    const float* query   = (const float*)d_in[0];
    const float* key     = (const float*)d_in[1];
    const float* gumbel  = (const float*)d_in[2];
    const float* w_refer = (const float*)d_in[3];
    const float* b_refer = (const float*)d_in[4];
    const float* w_attn  = (const float*)d_in[5];
    const float* b_attn  = (const float*)d_in[6];
    const float* w_mask  = (const float*)d_in[7];
    const float* b_mask  = (const float*)d_in[8];
    const float* w_off   = (const float*)d_in[9];
    const float* b_off   = (const float*)d_in[10];
    const int*   temp    = (const int*)d_in[11];
    float* out = (float*)d_out;

    u16*    kf16 = (u16*)d_ws;                                          // 16.78 MB
    float4* wgt  = (float4*)((char*)d_ws + (size_t)NB * NP * NC * 2);   // 4.72 MB
    uint2*  offs = (uint2*)((char*)wgt + (size_t)NB * NK * NP * 16);    // 2.36 MB
    float*  hd   = (float*)((char*)offs + (size_t)NB * NK * NP * 8);    // 4.72 MB

    kf_gemm<<<dim3(256, 2), 256, 0, stream>>>(key, w_refer, b_refer, kf16);
    hd_gemm<<<256, 256, 0, stream>>>(query, w_attn, b_attn, w_mask, b_mask, w_off, b_off, hd);
    meta_pass<<<256, 128, 0, stream>>>(hd, gumbel, temp, wgt, offs);
    sample_pass<<<NB * NH, 512, 0, stream>>>(kf16, wgt, offs, out);
}

// Round 6
// 62.100 us; speedup vs baseline: 4.1991x; 1.0527x over previous
//
#include <hip/hip_runtime.h>

typedef unsigned short u16;
typedef __attribute__((ext_vector_type(8))) short bf16x8;
typedef __attribute__((ext_vector_type(4))) float f32x4;

__device__ __forceinline__ u16 f2bf(float f) {
    unsigned u = __float_as_uint(f);
    unsigned r = (u + 0x7fffu + ((u >> 16) & 1u)) >> 16;
    return (u16)r;
}
__device__ __forceinline__ float bf2f(u16 h) {
    union { unsigned u; float f; } x; x.u = ((unsigned)h) << 16; return x.f;
}

#define NB 8
#define NC 256
#define NK 9
#define NH 64
#define NW 64
#define NP 4096
#define BAND 320            // 5 rows x 64 px band; |dy|>2 ~ P=4e-10 -> exact escape path
#define SB_STRIDE 328       // u16 stride for in-place bf16 B tile (656B rows)
#define KS_STRIDE 264       // u16 stride for key tile rows (528B)

// -------- pass 1: kf16[b][c][px] = bf16(w_refer @ key + b), BM=256 BN=64, key staged once ----
__global__ __launch_bounds__(256) void kf_gemm(const float* __restrict__ key,
                                               const float* __restrict__ w_refer,
                                               const float* __restrict__ b_refer,
                                               u16* __restrict__ kf16)
{
    __shared__ u16 K_s[64 * KS_STRIDE];    // [px][k] bf16, 33.8 KB
    const int bid = blockIdx.x;            // 512 = 8 b x 64 px-tiles
    const int b   = bid >> 6;
    const int p0  = (bid & 63) << 6;
    const int t = threadIdx.x;
    const int lane = t & 63, wid = t >> 6;
    const int fr = lane & 15, kq = (lane >> 4) << 3;
    const int co0w = wid << 6;             // wave covers co [co0w, co0w+64)

    // stage key tile 64px x 256k -> LDS bf16 transposed [px][k]
    #pragma unroll
    for (int rep = 0; rep < 16; ++rep) {
        int k = (rep << 4) + (t >> 4), px4 = (t & 15) << 2;
        float4 v = *(const float4*)&key[((size_t)b * NC + k) * NP + p0 + px4];
        K_s[(px4 + 0) * KS_STRIDE + k] = f2bf(v.x);
        K_s[(px4 + 1) * KS_STRIDE + k] = f2bf(v.y);
        K_s[(px4 + 2) * KS_STRIDE + k] = f2bf(v.z);
        K_s[(px4 + 3) * KS_STRIDE + k] = f2bf(v.w);
    }
    __syncthreads();

    f32x4 acc[4][4];
    #pragma unroll
    for (int i = 0; i < 4; ++i)
        #pragma unroll
        for (int j = 0; j < 4; ++j) acc[i][j] = (f32x4){0.f, 0.f, 0.f, 0.f};

    for (int ks = 0; ks < 8; ++ks) {
        const int k0 = (ks << 5) + kq;
        bf16x8 af[4], bfv[4];
        #pragma unroll
        for (int mi = 0; mi < 4; ++mi) {
            const float* src = &w_refer[(size_t)(co0w + (mi << 4) + fr) * NC + k0];
            float4 v0 = *(const float4*)src;
            float4 v1 = *(const float4*)(src + 4);
            bf16x8 a;
            a[0] = (short)f2bf(v0.x); a[1] = (short)f2bf(v0.y);
            a[2] = (short)f2bf(v0.z); a[3] = (short)f2bf(v0.w);
            a[4] = (short)f2bf(v1.x); a[5] = (short)f2bf(v1.y);
            a[6] = (short)f2bf(v1.z); a[7] = (short)f2bf(v1.w);
            af[mi] = a;
        }
        #pragma unroll
        for (int ni = 0; ni < 4; ++ni)
            bfv[ni] = *(const bf16x8*)&K_s[((ni << 4) + fr) * KS_STRIDE + k0];
        #pragma unroll
        for (int mi = 0; mi < 4; ++mi)
            #pragma unroll
            for (int ni = 0; ni < 4; ++ni)
                acc[mi][ni] = __builtin_amdgcn_mfma_f32_16x16x32_bf16(af[mi], bfv[ni], acc[mi][ni], 0, 0, 0);
    }
    const int col = lane & 15, rbase = (lane >> 4) << 2;
    #pragma unroll
    for (int mi = 0; mi < 4; ++mi) {
        #pragma unroll
        for (int rr = 0; rr < 4; ++rr) {
            int co = co0w + (mi << 4) + rbase + rr;
            float bias = b_refer[co];
            u16* dst = &kf16[((size_t)b * NC + co) * NP + p0 + col];
            #pragma unroll
            for (int ni = 0; ni < 4; ++ni)
                dst[ni << 4] = f2bf(acc[mi][ni][rr] + bias);
        }
    }
}

// ---- pass 2: heads via MFMA -> LDS transpose -> softmaxes + bilinear meta (fused) ----
__global__ __launch_bounds__(256) void head_meta(const float* __restrict__ query,
                                                 const float* __restrict__ gumbel,
                                                 const float* __restrict__ w_attn, const float* __restrict__ b_attn,
                                                 const float* __restrict__ w_mask, const float* __restrict__ b_mask,
                                                 const float* __restrict__ w_off,  const float* __restrict__ b_off,
                                                 const int* __restrict__ temp_p,
                                                 float4* __restrict__ wgt, uint2* __restrict__ offs)
{
    __shared__ u16 A[48][264];             // bf16 head weights (36 + 12 zero rows), 25.3 KB
    __shared__ float hdT[128][41];         // transposed head outputs [px][o], 21 KB
    const int pt = blockIdx.x;             // 256 tiles of 128 px
    const int b  = pt >> 5;
    const int p0 = (pt & 31) << 7;
    const int t = threadIdx.x;
    const int lane = t & 63, wn = t >> 6;  // 4 waves, 32 px each
    const int fr = lane & 15, kq = (lane >> 4) << 3;

    for (int i = t; i < 1152; i += 256) {  // 36 rows x 32 octets
        int o = i >> 5, c = (i & 31) << 3;
        const float* src = (o < 9) ? &w_attn[o * NC + c]
                       : (o < 18 ? &w_mask[(o - 9) * NC + c]
                                 : &w_off[(o - 18) * NC + c]);
        float4 v0 = *(const float4*)src;
        float4 v1 = *(const float4*)(src + 4);
        bf16x8 a;
        a[0] = (short)f2bf(v0.x); a[1] = (short)f2bf(v0.y);
        a[2] = (short)f2bf(v0.z); a[3] = (short)f2bf(v0.w);
        a[4] = (short)f2bf(v1.x); a[5] = (short)f2bf(v1.y);
        a[6] = (short)f2bf(v1.z); a[7] = (short)f2bf(v1.w);
        *(bf16x8*)&A[o][c] = a;
    }
    for (int i = t; i < 384; i += 256) {
        bf16x8 z = {0,0,0,0,0,0,0,0};
        *(bf16x8*)&A[36 + (i >> 5)][(i & 31) << 3] = z;
    }
    __syncthreads();

    f32x4 acc[3][2];
    #pragma unroll
    for (int i = 0; i < 3; ++i)
        #pragma unroll
        for (int j = 0; j < 2; ++j) acc[i][j] = (f32x4){0.f, 0.f, 0.f, 0.f};

    for (int ks = 0; ks < 8; ++ks) {
        const int k0 = (ks << 5) + kq;
        bf16x8 af[3], bfv[2];
        #pragma unroll
        for (int mi = 0; mi < 3; ++mi)
            af[mi] = *(const bf16x8*)&A[(mi << 4) + fr][k0];
        #pragma unroll
        for (int ni = 0; ni < 2; ++ni) {
            const float* src = &query[((size_t)b * NC + k0) * NP + p0 + (wn << 5) + (ni << 4) + fr];
            bf16x8 bv;
            #pragma unroll
            for (int j = 0; j < 8; ++j) bv[j] = (short)f2bf(src[(size_t)j * NP]);
            bfv[ni] = bv;
        }
        #pragma unroll
        for (int mi = 0; mi < 3; ++mi)
            #pragma unroll
            for (int ni = 0; ni < 2; ++ni)
                acc[mi][ni] = __builtin_amdgcn_mfma_f32_16x16x32_bf16(af[mi], bfv[ni], acc[mi][ni], 0, 0, 0);
    }
    // epilogue -> LDS transpose (bias folded)
    const int col = lane & 15, rbase = (lane >> 4) << 2;
    #pragma unroll
    for (int mi = 0; mi < 3; ++mi) {
        #pragma unroll
        for (int rr = 0; rr < 4; ++rr) {
            int o = (mi << 4) + rbase + rr;
            if (o < 36) {
                float bias = (o < 9) ? b_attn[o] : (o < 18) ? b_mask[o - 9] : b_off[o - 18];
                #pragma unroll
                for (int ni = 0; ni < 2; ++ni)
                    hdT[(wn << 5) + (ni << 4) + col][o] = acc[mi][ni][rr] + bias;
            }
        }
    }
    __syncthreads();

    if (t < 128) {
        const int pxg = p0 + t;                   // global pixel in batch b
        const int row = pxg >> 6, xcol = pxg & 63;
        float v[36];
        #pragma unroll
        for (int o = 0; o < 36; ++o) v[o] = hdT[t][o];

        int ti = temp_p[0];
        float tempf = (ti >= 1 && ti < (1 << 23)) ? (float)ti : __int_as_float(ti);
        float am[9], hs[9];
        float mx = -1e30f;
        #pragma unroll
        for (int k = 0; k < 9; ++k) {
            am[k] = v[k];
            float g = gumbel[((size_t)b * NK + k) * NP + pxg];
            hs[k] = (v[9 + k] + g) / tempf;
            mx = fmaxf(mx, hs[k]);
        }
        float ssum = 0.f;
        #pragma unroll
        for (int k = 0; k < 9; ++k) { hs[k] = __expf(hs[k] - mx); ssum += hs[k]; }
        float inv = 1.f / ssum;
        float lg[9]; float mx2 = -1e30f;
        #pragma unroll
        for (int k = 0; k < 9; ++k) { lg[k] = am[k] * (hs[k] * inv); mx2 = fmaxf(mx2, lg[k]); }
        float s2 = 0.f;
        #pragma unroll
        for (int k = 0; k < 9; ++k) { lg[k] = __expf(lg[k] - mx2); s2 += lg[k]; }
        float inv2 = 1.f / s2;
        #pragma unroll
        for (int k = 0; k < 9; ++k) {
            float a = lg[k] * inv2;
            float pyv = (float)row  + v[18 + k];       // dy = off chan k (bias folded)
            float pxv = (float)xcol + v[19 + k];       // dx = off chan k+1 (!)
            float y0f = floorf(pyv), x0f = floorf(pxv);
            float wy = pyv - y0f, wx = pxv - x0f;
            int y0 = (int)y0f, x0 = (int)x0f;
            int y1 = y0 + 1, x1 = x0 + 1;
            float vy0 = (y0 >= 0 && y0 < NH) ? 1.f : 0.f;
            float vy1 = (y1 >= 0 && y1 < NH) ? 1.f : 0.f;
            float vx0 = (x0 >= 0 && x0 < NW) ? 1.f : 0.f;
            float vx1 = (x1 >= 0 && x1 < NW) ? 1.f : 0.f;
            int y0c = min(max(y0, 0), NH - 1), y1c = min(max(y1, 0), NH - 1);
            int x0c = min(max(x0, 0), NW - 1), x1c = min(max(x1, 0), NW - 1);
            unsigned o00 = (unsigned)(y0c * NW + x0c), o01 = (unsigned)(y0c * NW + x1c);
            unsigned o10 = (unsigned)(y1c * NW + x0c), o11 = (unsigned)(y1c * NW + x1c);
            size_t idx = ((size_t)b * NK + k) * NP + pxg;
            wgt[idx]  = make_float4(a * (1.f - wy) * (1.f - wx) * vy0 * vx0,
                                    a * (1.f - wy) * wx * vy0 * vx1,
                                    a * wy * (1.f - wx) * vy1 * vx0,
                                    a * wy * wx * vy1 * vx1);
            offs[idx] = make_uint2(o00 | (o01 << 16), o10 | (o11 << 16));
        }
    }
}

// ------- pass 3: banded scatter-GEMM: out[c][px] = kf16[c][band] @ S[band][px] -----------
__global__ __launch_bounds__(512, 4) void sample_pass(const u16* __restrict__ kf16,
                                                      const float4* __restrict__ wgt,
                                                      const uint2* __restrict__ offs,
                                                      float* __restrict__ out)
{
    __shared__ float Sf[64][BAND];                 // exactly 80 KB -> 2 blocks/CU

    const int bid = blockIdx.x;
    const int b = bid & 7, row = bid >> 3;         // b = bid%8 -> XCD/L2 batch affinity
    const int t = threadIdx.x;
    const int lane = t & 63, wid = t >> 6;
    const int fr = lane & 15, kq = (lane >> 4) << 3;
    const int c0 = wid << 5;
    const int ylo = min(max(row - 2, 0), NH - 5);
    const int base = ylo << 6;
    const u16* kfb = kf16 + (size_t)b * NC * NP + base;

    // --- prefetch meta (consumed in scatter) ---
    const int px = t & 63, kg = t >> 6;
    size_t idx0 = ((size_t)b * NK + kg) * NP + (row << 6) + px;
    float4 wv0 = wgt[idx0];
    uint2  ov0 = offs[idx0];
    float4 wv1 = make_float4(0.f, 0.f, 0.f, 0.f);
    uint2  ov1 = make_uint2(0u, 0u);
    if (kg == 0) {
        size_t idx1 = ((size_t)b * NK + 8) * NP + (row << 6) + px;
        wv1 = wgt[idx1]; ov1 = offs[idx1];
    }

    // --- zero S ---
    #pragma unroll
    for (int i = 0; i < 10; ++i)
        ((float4*)Sf)[t + (i << 9)] = (float4){0.f, 0.f, 0.f, 0.f};
    __syncthreads();

    // --- scatter 36 weighted corners per px (f32 atomics; escapes -> flag) ---
    bool esc = false;
    #pragma unroll
    for (int s = 0; s < 2; ++s) {
        if (s == 1 && kg != 0) break;
        float4 wv = s ? wv1 : wv0;
        uint2  ov = s ? ov1 : ov0;
        int   o4[4] = { (int)(ov.x & 0xffffu), (int)(ov.x >> 16),
                        (int)(ov.y & 0xffffu), (int)(ov.y >> 16) };
        float w4[4] = { wv.x, wv.y, wv.z, wv.w };
        #pragma unroll
        for (int c = 0; c < 4; ++c) {
            int u = o4[c] - base;
            if ((unsigned)u < (unsigned)BAND) atomicAdd(&Sf[px][u], w4[c]);
            else esc = true;
        }
    }
    __syncthreads();

    // --- issue A prefetch (4 K-steps deep); pack barriers below cover the latency ---
    bf16x8 apre[4][2];
    #pragma unroll
    for (int s = 0; s < 4; ++s)
        #pragma unroll
        for (int mi = 0; mi < 2; ++mi)
            apre[s][mi] = *(const bf16x8*)&kfb[(size_t)(c0 + (mi << 4) + fr) * NP + (s << 5) + kq];

    // --- in-place pack S -> bf16, one record in flight ({read, barrier, write} x5) ---
    // record r reads f32 rows [12.8r,12.8(r+1)); its writes end at byte 8397(r+1)
    // < 16384(r+1) = start of record r+1's reads  -> no clobber.
    u16* Sb = (u16*)&Sf[0][0];                     // stride SB_STRIDE u16 (656B rows)
    #pragma unroll
    for (int r = 0; r < 5; ++r) {
        int i = t + (r << 9);
        int p = i / 40, j = (i % 40) << 3;
        float4 a = *(const float4*)&Sf[p][j];
        float4 c = *(const float4*)&Sf[p][j + 4];
        bf16x8 q;
        q[0] = (short)f2bf(a.x); q[1] = (short)f2bf(a.y);
        q[2] = (short)f2bf(a.z); q[3] = (short)f2bf(a.w);
        q[4] = (short)f2bf(c.x); q[5] = (short)f2bf(c.y);
        q[6] = (short)f2bf(c.z); q[7] = (short)f2bf(c.w);
        __syncthreads();
        *(bf16x8*)&Sb[p * SB_STRIDE + j] = q;
    }
    __syncthreads();

    // --- MFMA: wave w -> c rows [w*32, w*32+32), 64 px, K = 320; A pipelined 4 deep ---
    f32x4 acc[2][4];
    #pragma unroll
    for (int i = 0; i < 2; ++i)
        #pragma unroll
        for (int j = 0; j < 4; ++j) acc[i][j] = (f32x4){0.f, 0.f, 0.f, 0.f};

    #pragma unroll
    for (int step = 0; step < 10; ++step) {
        bf16x8 a0 = apre[step & 3][0], a1 = apre[step & 3][1];
        if (step + 4 < 10) {
            #pragma unroll
            for (int mi = 0; mi < 2; ++mi)
                apre[step & 3][mi] =
                    *(const bf16x8*)&kfb[(size_t)(c0 + (mi << 4) + fr) * NP + ((step + 4) << 5) + kq];
        }
        bf16x8 bfv[4];
        #pragma unroll
        for (int ni = 0; ni < 4; ++ni)
            bfv[ni] = *(const bf16x8*)&Sb[((ni << 4) + fr) * SB_STRIDE + (step << 5) + kq];
        #pragma unroll
        for (int ni = 0; ni < 4; ++ni) {
            acc[0][ni] = __builtin_amdgcn_mfma_f32_16x16x32_bf16(a0, bfv[ni], acc[0][ni], 0, 0, 0);
            acc[1][ni] = __builtin_amdgcn_mfma_f32_16x16x32_bf16(a1, bfv[ni], acc[1][ni], 0, 0, 0);
        }
    }

    // --- store (block-exclusive out region) ---
    const int col = lane & 15, rbase = (lane >> 4) << 2;
    float* ob = out + (size_t)b * NC * NP + (row << 6);
    #pragma unroll
    for (int mi = 0; mi < 2; ++mi) {
        #pragma unroll
        for (int rr = 0; rr < 4; ++rr) {
            int c = c0 + (mi << 4) + rbase + rr;
            #pragma unroll
            for (int ni = 0; ni < 4; ++ni)
                ob[(size_t)c * NP + (ni << 4) + col] = acc[mi][ni][rr];
        }
    }

    // --- rare out-of-band corners (exact fallback; ~never executes) ---
    __syncthreads();
    if (esc) {
        for (int s = 0; s < (kg == 0 ? 2 : 1); ++s) {
            int k = s ? 8 : kg;
            size_t idx = ((size_t)b * NK + k) * NP + (row << 6) + px;
            float4 wv = wgt[idx];
            uint2  ov = offs[idx];
            int   o4[4] = { (int)(ov.x & 0xffffu), (int)(ov.x >> 16),
                            (int)(ov.y & 0xffffu), (int)(ov.y >> 16) };
            float w4[4] = { wv.x, wv.y, wv.z, wv.w };
            for (int c = 0; c < 4; ++c) {
                int u = o4[c] - base;
                if ((unsigned)u >= (unsigned)BAND) {
                    for (int cc = 0; cc < NC; ++cc)
                        atomicAdd(&ob[(size_t)cc * NP + px],
                                  w4[c] * bf2f(kf16[((size_t)b * NC + cc) * NP + o4[c]]));
                }
            }
        }
    }
}

extern "C" void kernel_launch(void* const* d_in, const int* in_sizes, int n_in,
                              void* d_out, int out_size, void* d_ws, size_t ws_size,
                              hipStream_t stream)
{
    const float* query   = (const float*)d_in[0];
    const float* key     = (const float*)d_in[1];
    const float* gumbel  = (const float*)d_in[2];
    const float* w_refer = (const float*)d_in[3];
    const float* b_refer = (const float*)d_in[4];
    const float* w_attn  = (const float*)d_in[5];
    const float* b_attn  = (const float*)d_in[6];
    const float* w_mask  = (const float*)d_in[7];
    const float* b_mask  = (const float*)d_in[8];
    const float* w_off   = (const float*)d_in[9];
    const float* b_off   = (const float*)d_in[10];
    const int*   temp    = (const int*)d_in[11];
    float* out = (float*)d_out;

    u16*    kf16 = (u16*)d_ws;                                          // 16.78 MB
    float4* wgt  = (float4*)((char*)d_ws + (size_t)NB * NP * NC * 2);   // 4.72 MB
    uint2*  offs = (uint2*)((char*)wgt + (size_t)NB * NK * NP * 16);    // 2.36 MB

    kf_gemm<<<512, 256, 0, stream>>>(key, w_refer, b_refer, kf16);
    head_meta<<<256, 256, 0, stream>>>(query, gumbel, w_attn, b_attn, w_mask, b_mask,
                                       w_off, b_off, temp, wgt, offs);
    sample_pass<<<512, 512, 0, stream>>>(kf16, wgt, offs, out);
}